// Round 1
// baseline (6884.876 us; speedup 1.0000x reference)
//
#include <hip/hip_runtime.h>

#define DH 15

// ---- stable tanh + derivative factors -------------------------------------
// t = tanh(u), s = sech^2(u) = 1-t^2, f2 = t'', f3 = t''', f4 = t''''
__device__ __forceinline__ void tanh_fs(float u0, float& t, float& s,
                                        float& f2, float& f3, float& f4) {
    float e = __builtin_amdgcn_exp2f(u0 * 2.885390081777927f); // exp(2*u0)
    float r = __builtin_amdgcn_rcpf(1.0f + e);
    t = 1.0f - 2.0f * r;
    s = 4.0f * r * (1.0f - r);           // = 4 e r^2, no inf*0, no cancellation
    f2 = -2.0f * t * s;
    f3 = s * (4.0f * t * t - 2.0f * s);
    f4 = 8.0f * t * s * (2.0f * s - t * t);
}

// jet composition h = tanh(u) for degree-4 jets (true derivatives, Faà di Bruno)
__device__ __forceinline__ void tanh_jet(const float u0, const float u1, const float u2,
                                         const float u3, const float u4, float h[5]) {
    float t, s, f2, f3, f4;
    tanh_fs(u0, t, s, f2, f3, f4);
    float u1s = u1 * u1;
    h[0] = t;
    h[1] = s * u1;
    h[2] = f2 * u1s + s * u2;
    h[3] = f3 * u1s * u1 + 3.0f * f2 * u1 * u2 + s * u3;
    h[4] = f4 * u1s * u1s + 6.0f * f3 * u1s * u2
         + f2 * (3.0f * u2 * u2 + 4.0f * u1 * u3) + s * u4;
}

// dense 15->15 + tanh on jets, weights from LDS (padded rows of 16 floats)
__device__ __forceinline__ void dense_tanh(float h[DH][5], const float (*sW)[16],
                                           const float* sB) {
    float u[DH][5];
#pragma unroll
    for (int j = 0; j < DH; ++j) {
        u[j][0] = sB[j];
        u[j][1] = 0.f; u[j][2] = 0.f; u[j][3] = 0.f; u[j][4] = 0.f;
    }
#pragma unroll
    for (int k = 0; k < DH; ++k) {
        const float4* row = reinterpret_cast<const float4*>(&sW[k][0]);
        float4 r0 = row[0], r1 = row[1], r2 = row[2], r3 = row[3];
        float w[16] = {r0.x, r0.y, r0.z, r0.w, r1.x, r1.y, r1.z, r1.w,
                       r2.x, r2.y, r2.z, r2.w, r3.x, r3.y, r3.z, r3.w};
        float h0 = h[k][0], h1 = h[k][1], h2 = h[k][2], h3 = h[k][3], h4 = h[k][4];
#pragma unroll
        for (int j = 0; j < DH; ++j) {
            u[j][0] += h0 * w[j];
            u[j][1] += h1 * w[j];
            u[j][2] += h2 * w[j];
            u[j][3] += h3 * w[j];
            u[j][4] += h4 * w[j];
        }
    }
#pragma unroll
    for (int j = 0; j < DH; ++j) {
        float hj[5];
        tanh_jet(u[j][0], u[j][1], u[j][2], u[j][3], u[j][4], hj);
        h[j][0] = hj[0]; h[j][1] = hj[1]; h[j][2] = hj[2];
        h[j][3] = hj[3]; h[j][4] = hj[4];
    }
}

// ---- main kernel: per-point degree-4 jet, reduce (w''''+1)^2 ----------------
__global__ void __launch_bounds__(256)
pinn_main(const float* __restrict__ x,
          const float* __restrict__ W1, const float* __restrict__ b1,
          const float* __restrict__ W2, const float* __restrict__ b2,
          const float* __restrict__ W3, const float* __restrict__ b3,
          const float* __restrict__ W4, const float* __restrict__ b4,
          double* __restrict__ partials, int N) {
    __shared__ float sW2[DH][16];
    __shared__ float sW3[DH][16];
    __shared__ float sW1[16], sB1[16], sB2[16], sB3[16], sW4[16];
    int tid = threadIdx.x;
    if (tid < DH * DH) {
        int k = tid / DH, j = tid % DH;
        sW2[k][j] = W2[tid];
        sW3[k][j] = W3[tid];
    }
    if (tid < DH) {
        sW1[tid] = W1[tid]; sB1[tid] = b1[tid]; sB2[tid] = b2[tid];
        sB3[tid] = b3[tid]; sW4[tid] = W4[tid];
        sW2[tid][15] = 0.f; sW3[tid][15] = 0.f;
    }
    __syncthreads();

    float acc = 0.0f;
    int idx0 = blockIdx.x * blockDim.x + threadIdx.x;
    int gsz = gridDim.x * blockDim.x;
    for (int i = idx0; i < N; i += gsz) {
        float xv = x[i];
        float h[DH][5];
        // layer 1: u = x*w + b, jet (u0, w, 0, 0, 0)
#pragma unroll
        for (int j = 0; j < DH; ++j) {
            float w = sW1[j];
            float t, s, f2, f3, f4;
            tanh_fs(xv * w + sB1[j], t, s, f2, f3, f4);
            float w2 = w * w;
            h[j][0] = t;
            h[j][1] = s * w;
            h[j][2] = f2 * w2;
            h[j][3] = f3 * w2 * w;
            h[j][4] = f4 * w2 * w2;
        }
        dense_tanh(h, sW2, sB2);
        dense_tanh(h, sW3, sB3);
        float out4 = 0.f;
#pragma unroll
        for (int k = 0; k < DH; ++k) out4 += h[k][4] * sW4[k];
        float resid = out4 + 1.0f;   // + P/(E*I) = 1
        acc += resid * resid;
    }

    // block reduction (deterministic)
    double a = (double)acc;
#pragma unroll
    for (int off = 32; off > 0; off >>= 1) a += __shfl_down(a, off, 64);
    __shared__ double red[4];
    int lane = tid & 63, wid = tid >> 6;
    if (lane == 0) red[wid] = a;
    __syncthreads();
    if (tid == 0) partials[blockIdx.x] = red[0] + red[1] + red[2] + red[3];
}

// ---- scalar full-jet eval from global weights (boundary points) -------------
__device__ void eval_all(float xv,
                         const float* W1, const float* b1,
                         const float* W2, const float* b2,
                         const float* W3, const float* b3,
                         const float* W4, const float* b4, float o[5]) {
    float h[DH][5], u[DH][5];
    for (int j = 0; j < DH; ++j) {
        float w = W1[j];
        float t, s, f2, f3, f4;
        tanh_fs(xv * w + b1[j], t, s, f2, f3, f4);
        float w2 = w * w;
        h[j][0] = t; h[j][1] = s * w; h[j][2] = f2 * w2;
        h[j][3] = f3 * w2 * w; h[j][4] = f4 * w2 * w2;
    }
    const float* Ws[2] = {W2, W3};
    const float* Bs[2] = {b2, b3};
    for (int L = 0; L < 2; ++L) {
        for (int j = 0; j < DH; ++j) {
            u[j][0] = Bs[L][j];
            u[j][1] = u[j][2] = u[j][3] = u[j][4] = 0.f;
        }
        for (int k = 0; k < DH; ++k)
            for (int j = 0; j < DH; ++j) {
                float w = Ws[L][k * DH + j];
                for (int c = 0; c < 5; ++c) u[j][c] += h[k][c] * w;
            }
        for (int j = 0; j < DH; ++j) {
            float hj[5];
            tanh_jet(u[j][0], u[j][1], u[j][2], u[j][3], u[j][4], hj);
            for (int c = 0; c < 5; ++c) h[j][c] = hj[c];
        }
    }
    for (int c = 0; c < 5; ++c) o[c] = (c == 0) ? b4[0] : 0.f;
    for (int k = 0; k < DH; ++k)
        for (int c = 0; c < 5; ++c) o[c] += h[k][c] * W4[k];
}

// ---- finish: reduce partials, boundary evals, write scalars -----------------
__global__ void __launch_bounds__(256)
pinn_finish(const double* __restrict__ partials, int nparts,
            const float* __restrict__ W1, const float* __restrict__ b1,
            const float* __restrict__ W2, const float* __restrict__ b2,
            const float* __restrict__ W3, const float* __restrict__ b3,
            const float* __restrict__ W4, const float* __restrict__ b4,
            float* __restrict__ out, int N, float* __restrict__ consts) {
    int tid = threadIdx.x;
    double a = 0.0;
    for (int i = tid; i < nparts; i += 256) a += partials[i];
#pragma unroll
    for (int off = 32; off > 0; off >>= 1) a += __shfl_down(a, off, 64);
    __shared__ double red[4];
    if ((tid & 63) == 0) red[tid >> 6] = a;
    __syncthreads();
    if (tid == 0) {
        double total = red[0] + red[1] + red[2] + red[3];
        float pdef = (float)(total / (double)N);
        float j0[5], jL[5];
        eval_all(0.0f, W1, b1, W2, b2, W3, b3, W4, b4, j0);
        eval_all(1.0f, W1, b1, W2, b2, W3, b3, W4, b4, jL);
        float lbw  = j0[0] * j0[0];
        float lbwx = j0[1] * j0[1];
        float rbM  = jL[2] * jL[2];
        float rbw  = jL[0] * jL[0];
        float loss = pdef + lbw + lbwx + rbM + rbw;   // reference add order
        consts[0] = loss; consts[1] = lbw; consts[2] = lbwx;
        consts[3] = rbM;  consts[4] = rbw;
        out[N] = pdef;   // pde_loss scalar
    }
}

// ---- fill: broadcast 5 constants into their [N] regions ---------------------
__global__ void __launch_bounds__(256)
pinn_fill(float* __restrict__ out, const float* __restrict__ consts, int N) {
    int r = blockIdx.y;                       // 0:loss 1:lbw 2:lbwx 3:rbM 4:rbw
    float c = consts[r];
    size_t base = (r == 0) ? 0 : ((size_t)r * (size_t)N + 1);
    float* p = out + base;
    size_t tid = (size_t)blockIdx.x * blockDim.x + threadIdx.x;
    size_t stride = (size_t)gridDim.x * blockDim.x;
    size_t head = ((16 - ((size_t)p & 15)) & 15) >> 2;  // floats to 16B align
    size_t n = (size_t)N;
    if (head > n) head = n;
    if (tid < head) p[tid] = c;
    size_t n4 = (n - head) >> 2;
    float4* p4 = reinterpret_cast<float4*>(p + head);
    float4 cv = {c, c, c, c};
    for (size_t i = tid; i < n4; i += stride) p4[i] = cv;
    size_t done = head + (n4 << 2);
    size_t t = done + tid;
    if (t < n) p[t] = c;
}

extern "C" void kernel_launch(void* const* d_in, const int* in_sizes, int n_in,
                              void* d_out, int out_size, void* d_ws, size_t ws_size,
                              hipStream_t stream) {
    const float* x  = (const float*)d_in[0];
    const float* W1 = (const float*)d_in[1];
    const float* b1 = (const float*)d_in[2];
    const float* W2 = (const float*)d_in[3];
    const float* b2 = (const float*)d_in[4];
    const float* W3 = (const float*)d_in[5];
    const float* b3 = (const float*)d_in[6];
    const float* W4 = (const float*)d_in[7];
    const float* b4 = (const float*)d_in[8];
    float* out = (float*)d_out;
    int N = in_sizes[0];

    float* consts = (float*)d_ws;                       // 8 floats @ offset 0
    double* partials = (double*)((char*)d_ws + 256);    // NB doubles @ 256

    int NB = 2048;
    size_t need = 256 + (size_t)NB * 8;
    if (ws_size < need) {
        NB = (int)((ws_size > 256 + 8) ? (ws_size - 256) / 8 : 1);
        if (NB < 1) NB = 1;
        if (NB > 2048) NB = 2048;
    }

    hipLaunchKernelGGL(pinn_main, dim3(NB), dim3(256), 0, stream,
                       x, W1, b1, W2, b2, W3, b3, W4, b4, partials, N);
    hipLaunchKernelGGL(pinn_finish, dim3(1), dim3(256), 0, stream,
                       partials, NB, W1, b1, W2, b2, W3, b3, W4, b4,
                       out, N, consts);
    int gx = (N / 4 + 255) / 256;
    if (gx > 1024) gx = 1024;
    if (gx < 1) gx = 1;
    hipLaunchKernelGGL(pinn_fill, dim3(gx, 5), dim3(256), 0, stream,
                       out, consts, N);
}

// Round 2
// 318.042 us; speedup vs baseline: 21.6477x; 21.6477x over previous
//
#include <hip/hip_runtime.h>

#define DH 15

// ---- stable tanh + derivative factors -------------------------------------
// t = tanh(u), s = sech^2(u), f2 = t'', f3 = t''', f4 = t''''
__device__ __forceinline__ void tanh_fs(float u0, float& t, float& s,
                                        float& f2, float& f3, float& f4) {
    float e = __builtin_amdgcn_exp2f(u0 * 2.885390081777927f); // exp(2*u0)
    float r = __builtin_amdgcn_rcpf(1.0f + e);
    t = 1.0f - 2.0f * r;
    s = 4.0f * r * (1.0f - r);           // no inf*0, no cancellation
    f2 = -2.0f * t * s;
    f3 = s * (4.0f * t * t - 2.0f * s);
    f4 = 8.0f * t * s * (2.0f * s - t * t);
}

// degree-4 jet composition h = tanh(u) (Faà di Bruno)
__device__ __forceinline__ void tanh_jet(float u0, float u1, float u2,
                                         float u3, float u4, float h[5]) {
    float t, s, f2, f3, f4;
    tanh_fs(u0, t, s, f2, f3, f4);
    float u1s = u1 * u1;
    h[0] = t;
    h[1] = s * u1;
    h[2] = f2 * u1s + s * u2;
    h[3] = f3 * u1s * u1 + 3.0f * f2 * u1 * u2 + s * u3;
    h[4] = f4 * u1s * u1s + 6.0f * f3 * u1s * u2
         + f2 * (3.0f * u2 * u2 + 4.0f * u1 * u3) + s * u4;
}

// dense 15->15 + tanh on jets, weights from LDS (padded rows of 16 floats).
// sched_barrier(0) per row bounds the scheduler's load-hoisting to the
// explicit 1-row prefetch, keeping live VGPRs ~200 (no scratch spill).
__device__ __forceinline__ void dense_tanh(float h[DH][5], const float (*sW)[16],
                                           const float* sB) {
    float u[DH][5];
#pragma unroll
    for (int j = 0; j < DH; ++j) {
        u[j][0] = sB[j];
        u[j][1] = 0.f; u[j][2] = 0.f; u[j][3] = 0.f; u[j][4] = 0.f;
    }
    const float4* rows = reinterpret_cast<const float4*>(&sW[0][0]);
    float4 c0 = rows[0], c1 = rows[1], c2 = rows[2], c3 = rows[3];
#pragma unroll
    for (int k = 0; k < DH; ++k) {
        float4 n0, n1, n2, n3;
        if (k + 1 < DH) {
            n0 = rows[4 * (k + 1) + 0]; n1 = rows[4 * (k + 1) + 1];
            n2 = rows[4 * (k + 1) + 2]; n3 = rows[4 * (k + 1) + 3];
        }
        float w[16] = {c0.x, c0.y, c0.z, c0.w, c1.x, c1.y, c1.z, c1.w,
                       c2.x, c2.y, c2.z, c2.w, c3.x, c3.y, c3.z, c3.w};
        float h0 = h[k][0], h1 = h[k][1], h2 = h[k][2], h3 = h[k][3], h4 = h[k][4];
#pragma unroll
        for (int j = 0; j < DH; ++j) {
            u[j][0] = fmaf(h0, w[j], u[j][0]);
            u[j][1] = fmaf(h1, w[j], u[j][1]);
            u[j][2] = fmaf(h2, w[j], u[j][2]);
            u[j][3] = fmaf(h3, w[j], u[j][3]);
            u[j][4] = fmaf(h4, w[j], u[j][4]);
        }
        __builtin_amdgcn_sched_barrier(0);
        if (k + 1 < DH) { c0 = n0; c1 = n1; c2 = n2; c3 = n3; }
    }
#pragma unroll
    for (int j = 0; j < DH; ++j) {
        float hj[5];
        tanh_jet(u[j][0], u[j][1], u[j][2], u[j][3], u[j][4], hj);
        h[j][0] = hj[0]; h[j][1] = hj[1]; h[j][2] = hj[2];
        h[j][3] = hj[3]; h[j][4] = hj[4];
        __builtin_amdgcn_sched_barrier(0);
    }
}

// full degree-4 jet through the MLP for one scalar x (LDS-staged weights)
__device__ __forceinline__ void jet_eval(float xv, const float* sW1, const float* sB1,
                                         const float (*sW2)[16], const float* sB2,
                                         const float (*sW3)[16], const float* sB3,
                                         const float* sW4, float bias4, float o[5]) {
    float h[DH][5];
#pragma unroll
    for (int j = 0; j < DH; ++j) {
        float w = sW1[j];
        float t, s, f2, f3, f4;
        tanh_fs(fmaf(xv, w, sB1[j]), t, s, f2, f3, f4);
        float w2 = w * w;
        h[j][0] = t;
        h[j][1] = s * w;
        h[j][2] = f2 * w2;
        h[j][3] = f3 * w2 * w;
        h[j][4] = f4 * w2 * w2;
        __builtin_amdgcn_sched_barrier(0);
    }
    dense_tanh(h, sW2, sB2);
    dense_tanh(h, sW3, sB3);
    o[0] = bias4; o[1] = 0.f; o[2] = 0.f; o[3] = 0.f; o[4] = 0.f;
#pragma unroll
    for (int k = 0; k < DH; ++k) {
        float w = sW4[k];
        o[0] = fmaf(h[k][0], w, o[0]);
        o[1] = fmaf(h[k][1], w, o[1]);
        o[2] = fmaf(h[k][2], w, o[2]);
        o[3] = fmaf(h[k][3], w, o[3]);
        o[4] = fmaf(h[k][4], w, o[4]);
    }
}

#define STAGE_WEIGHTS()                                                        \
    __shared__ float sW2[DH][16];                                              \
    __shared__ float sW3[DH][16];                                              \
    __shared__ float sW1[16], sB1[16], sB2[16], sB3[16], sW4[16];              \
    __shared__ float sBias4;                                                   \
    {                                                                          \
        int t_ = threadIdx.x;                                                  \
        if (t_ < DH * DH) {                                                    \
            int k_ = t_ / DH, j_ = t_ % DH;                                    \
            sW2[k_][j_] = W2[t_];                                              \
            sW3[k_][j_] = W3[t_];                                              \
        }                                                                      \
        if (t_ < DH) {                                                         \
            sW1[t_] = W1[t_]; sB1[t_] = b1[t_]; sB2[t_] = b2[t_];              \
            sB3[t_] = b3[t_]; sW4[t_] = W4[t_];                                \
            sW2[t_][15] = 0.f; sW3[t_][15] = 0.f;                              \
        }                                                                      \
        if (t_ == 0) sBias4 = b4[0];                                           \
        __syncthreads();                                                       \
    }

// ---- main kernel: per-point degree-4 jet, reduce (w''''+1)^2 ----------------
__global__ void __launch_bounds__(256)
pinn_main(const float* __restrict__ x,
          const float* __restrict__ W1, const float* __restrict__ b1,
          const float* __restrict__ W2, const float* __restrict__ b2,
          const float* __restrict__ W3, const float* __restrict__ b3,
          const float* __restrict__ W4, const float* __restrict__ b4,
          double* __restrict__ partials, int N) {
    STAGE_WEIGHTS();
    int tid = threadIdx.x;
    float acc = 0.0f;
    int idx0 = blockIdx.x * blockDim.x + tid;
    int gsz = gridDim.x * blockDim.x;
    for (int i = idx0; i < N; i += gsz) {
        float xv = x[i];
        float o[5];
        jet_eval(xv, sW1, sB1, sW2, sB2, sW3, sB3, sW4, sBias4, o);
        float resid = o[4] + 1.0f;     // + P/(E*I) = 1
        acc = fmaf(resid, resid, acc);
    }

    // deterministic block reduction
    double a = (double)acc;
#pragma unroll
    for (int off = 32; off > 0; off >>= 1) a += __shfl_down(a, off, 64);
    __shared__ double red[4];
    int lane = tid & 63, wid = tid >> 6;
    if (lane == 0) red[wid] = a;
    __syncthreads();
    if (tid == 0) partials[blockIdx.x] = red[0] + red[1] + red[2] + red[3];
}

// ---- finish: reduce partials, boundary evals (per-lane, unrolled), scalars --
__global__ void __launch_bounds__(256)
pinn_finish(const double* __restrict__ partials, int nparts,
            const float* __restrict__ W1, const float* __restrict__ b1,
            const float* __restrict__ W2, const float* __restrict__ b2,
            const float* __restrict__ W3, const float* __restrict__ b3,
            const float* __restrict__ W4, const float* __restrict__ b4,
            float* __restrict__ out, int N, float* __restrict__ consts) {
    STAGE_WEIGHTS();
    int tid = threadIdx.x;
    double a = 0.0;
    for (int i = tid; i < nparts; i += 256) a += partials[i];
#pragma unroll
    for (int off = 32; off > 0; off >>= 1) a += __shfl_down(a, off, 64);
    __shared__ double red[4];
    if ((tid & 63) == 0) red[tid >> 6] = a;
    __syncthreads();

    // lanes of wave 0 evaluate boundary jets (even lanes x=0, odd lanes x=1),
    // fully unrolled (no scratch). thread 0 shuffles lane 1's result over.
    __shared__ float jsh[2][5];
    if (tid < 64) {
        float xv = (tid & 1) ? 1.0f : 0.0f;
        float o[5];
        jet_eval(xv, sW1, sB1, sW2, sB2, sW3, sB3, sW4, sBias4, o);
        if (tid < 2) {
#pragma unroll
            for (int c = 0; c < 5; ++c) jsh[tid][c] = o[c];
        }
    }
    __syncthreads();
    if (tid == 0) {
        double total = red[0] + red[1] + red[2] + red[3];
        float pdef = (float)(total / (double)N);
        float lbw  = jsh[0][0] * jsh[0][0];
        float lbwx = jsh[0][1] * jsh[0][1];
        float rbM  = jsh[1][2] * jsh[1][2];
        float rbw  = jsh[1][0] * jsh[1][0];
        float loss = pdef + lbw + lbwx + rbM + rbw;  // reference add order
        consts[0] = loss; consts[1] = lbw; consts[2] = lbwx;
        consts[3] = rbM;  consts[4] = rbw;
        out[N] = pdef;   // pde_loss scalar
    }
}

// ---- fill: broadcast 5 constants into their [N] regions ---------------------
__global__ void __launch_bounds__(256)
pinn_fill(float* __restrict__ out, const float* __restrict__ consts, int N) {
    int r = blockIdx.y;                       // 0:loss 1:lbw 2:lbwx 3:rbM 4:rbw
    float c = consts[r];
    size_t base = (r == 0) ? 0 : ((size_t)r * (size_t)N + 1);
    float* p = out + base;
    size_t tid = (size_t)blockIdx.x * blockDim.x + threadIdx.x;
    size_t stride = (size_t)gridDim.x * blockDim.x;
    size_t head = ((16 - ((size_t)p & 15)) & 15) >> 2;  // floats to 16B align
    size_t n = (size_t)N;
    if (head > n) head = n;
    if (tid < head) p[tid] = c;
    size_t n4 = (n - head) >> 2;
    float4* p4 = reinterpret_cast<float4*>(p + head);
    float4 cv = {c, c, c, c};
    for (size_t i = tid; i < n4; i += stride) p4[i] = cv;
    size_t done = head + (n4 << 2);
    size_t t = done + tid;
    if (t < n) p[t] = c;
}

extern "C" void kernel_launch(void* const* d_in, const int* in_sizes, int n_in,
                              void* d_out, int out_size, void* d_ws, size_t ws_size,
                              hipStream_t stream) {
    const float* x  = (const float*)d_in[0];
    const float* W1 = (const float*)d_in[1];
    const float* b1 = (const float*)d_in[2];
    const float* W2 = (const float*)d_in[3];
    const float* b2 = (const float*)d_in[4];
    const float* W3 = (const float*)d_in[5];
    const float* b3 = (const float*)d_in[6];
    const float* W4 = (const float*)d_in[7];
    const float* b4 = (const float*)d_in[8];
    float* out = (float*)d_out;
    int N = in_sizes[0];

    float* consts = (float*)d_ws;                       // 8 floats @ offset 0
    double* partials = (double*)((char*)d_ws + 256);    // NB doubles @ 256

    int NB = 2048;
    size_t need = 256 + (size_t)NB * 8;
    if (ws_size < need) {
        NB = (int)((ws_size > 256 + 8) ? (ws_size - 256) / 8 : 1);
        if (NB < 1) NB = 1;
        if (NB > 2048) NB = 2048;
    }

    hipLaunchKernelGGL(pinn_main, dim3(NB), dim3(256), 0, stream,
                       x, W1, b1, W2, b2, W3, b3, W4, b4, partials, N);
    hipLaunchKernelGGL(pinn_finish, dim3(1), dim3(256), 0, stream,
                       partials, NB, W1, b1, W2, b2, W3, b3, W4, b4,
                       out, N, consts);
    int gx = (N / 4 + 255) / 256;
    if (gx > 1024) gx = 1024;
    if (gx < 1) gx = 1;
    hipLaunchKernelGGL(pinn_fill, dim3(gx, 5), dim3(256), 0, stream,
                       out, consts, N);
}